// Round 4
// baseline (93.612 us; speedup 1.0000x reference)
//
#include <hip/hip_runtime.h>

#define W    256
#define H    256
#define RPW  32                 // output rows per wave
#define NLD  (RPW + 6)          // 38 processed rows per wave (3 halo each side)

__global__ __launch_bounds__(256, 5)
void rg_kernel(const float* __restrict__ x, float* __restrict__ out) {
    const int lane = threadIdx.x & 63;      // wave spans the full 256-col row
    const int wv   = threadIdx.x >> 6;      // 0..3: which 32-row strip
    const int c0   = lane << 2;

    const int half  = blockIdx.x & 1;       // top/bottom half of the plane
    const int plane = blockIdx.x >> 1;      // b*64 + c
    const int r0    = half * 128 + wv * RPW;

    const float* xp = x + (size_t)plane * (size_t)(W * H);
    const int b = plane >> 6, cch = plane & 63;
    float* outx = out + ((size_t)(b * 128 + cch)) * (size_t)(W * H);
    float* outr = outx + (size_t)64 * (W * H);

    // per-column reciprocal horizontal counts (hoisted)
    float4 rch;
    rch.x = __builtin_amdgcn_rcpf((float)(min(c0 + 3, W - 1) - max(c0 - 3, 0) + 1));
    rch.y = __builtin_amdgcn_rcpf((float)(min(c0 + 4, W - 1) - max(c0 - 2, 0) + 1));
    rch.z = __builtin_amdgcn_rcpf((float)(min(c0 + 5, W - 1) - max(c0 - 1, 0) + 1));
    rch.w = __builtin_amdgcn_rcpf((float)(min(c0 + 6, W - 1) - max(c0 + 0, 0) + 1));

    float4 h[7];                            // rotating hsum window (static idx only)
    float4 eq[7];                           // rotating exp(x) queue (static idx only)

    for (int k = 0; k < 6; ++k) {           // 6 x 7 = 42 >= NLD iterations
        #pragma unroll
        for (int u = 0; u < 7; ++u) {
            const int i = k * 7 + u;        // i % 7 == u (compile-time index)

            if (i < NLD) {                  // wave-uniform
                const int row = r0 - 3 + i;
                if ((unsigned)row < (unsigned)H) {     // wave-uniform
                    float4 v = *(const float4*)(xp + row * W + c0);
                    // concat first half: copy of x, straight from registers
                    *(float4*)(outx + (size_t)row * W + c0) = v;
                    // exp(x) queue for the emit 3 iterations later
                    float4 e;
                    e.x = __expf(v.x); e.y = __expf(v.y);
                    e.z = __expf(v.z); e.w = __expf(v.w);
                    eq[u] = e;
                    // d = 0.5*exp(x^2 - x)
                    float4 d;
                    d.x = 0.5f * __expf(__fmaf_rn(v.x, v.x, -v.x));
                    d.y = 0.5f * __expf(__fmaf_rn(v.y, v.y, -v.y));
                    d.z = 0.5f * __expf(__fmaf_rn(v.z, v.z, -v.z));
                    d.w = 0.5f * __expf(__fmaf_rn(v.w, v.w, -v.w));
                    // horizontal 7-sum via neighbor-lane shuffles
                    float dmy = __shfl_up(d.y, 1);
                    float dmz = __shfl_up(d.z, 1);
                    float dmw = __shfl_up(d.w, 1);
                    float dpx = __shfl_down(d.x, 1);
                    float dpy = __shfl_down(d.y, 1);
                    float dpz = __shfl_down(d.z, 1);
                    if (lane == 0)  { dmy = 0.f; dmz = 0.f; dmw = 0.f; }
                    if (lane == 63) { dpx = 0.f; dpy = 0.f; dpz = 0.f; }
                    const float s = (d.x + d.y) + (d.z + d.w);
                    float4 hh;
                    hh.x = ((dmy + dmz) + dmw) + s;
                    hh.y = (dmz + dmw) + (s + dpx);
                    hh.z = dmw + (s + (dpx + dpy));
                    hh.w = s + ((dpx + dpy) + dpz);
                    h[u] = hh;
                } else {
                    h[u] = make_float4(0.f, 0.f, 0.f, 0.f);
                }
            }

            if (i >= 6 && i < NLD) {        // emit center row c = r0 + i - 6
                // window holds rows c-3..c+3 (order irrelevant for the sum)
                float4 vs;
                vs.x = ((h[0].x + h[1].x) + (h[2].x + h[3].x)) + ((h[4].x + h[5].x) + h[6].x);
                vs.y = ((h[0].y + h[1].y) + (h[2].y + h[3].y)) + ((h[4].y + h[5].y) + h[6].y);
                vs.z = ((h[0].z + h[1].z) + (h[2].z + h[3].z)) + ((h[4].z + h[5].z) + h[6].z);
                vs.w = ((h[0].w + h[1].w) + (h[2].w + h[3].w)) + ((h[4].w + h[5].w) + h[6].w);

                const int c = r0 + i - 6;
                const float rcv = __builtin_amdgcn_rcpf(
                    (float)(min(c + 3, H - 1) - max(c - 3, 0) + 1));

                const float4 e = eq[(u + 4) % 7];   // exp(x) at center row (static idx)
                float4 r;
                r.x = vs.x * (rch.x * rcv) * e.x;
                r.y = vs.y * (rch.y * rcv) * e.y;
                r.z = vs.z * (rch.z * rcv) * e.z;
                r.w = vs.w * (rch.w * rcv) * e.w;
                *(float4*)(outr + (size_t)c * W + c0) = r;
            }
        }
    }
}

extern "C" void kernel_launch(void* const* d_in, const int* in_sizes, int n_in,
                              void* d_out, int out_size, void* d_ws, size_t ws_size,
                              hipStream_t stream) {
    const float* x = (const float*)d_in[0];
    float* out = (float*)d_out;
    int n = in_sizes[0];
    int planes = n / (W * H);               // 512
    int grid = planes * 2;                  // 1024 blocks: 4 waves x 32 rows = half plane
    rg_kernel<<<dim3(grid), dim3(256), 0, stream>>>(x, out);
}

// Round 6
// 72.040 us; speedup vs baseline: 1.2995x; 1.2995x over previous
//
#include <hip/hip_runtime.h>

#define W   256
#define H   256
#define TH  32                  // output rows per block
#define NR  38                  // staged hsum rows (32 + 2*3 halo)

typedef float f4 __attribute__((ext_vector_type(4)));   // clang vector: ok for nontemporal builtins

__device__ __forceinline__ void nt_store(float* p, float4 v) {
    f4 t; t.x = v.x; t.y = v.y; t.z = v.z; t.w = v.w;
    __builtin_nontemporal_store(t, (f4*)p);
}

__global__ __launch_bounds__(512, 8)
void rg_kernel(const float* __restrict__ x, float* __restrict__ out) {
    __shared__ float hs[NR][W];             // horizontal 7-sums, 38 KB

    const int lane = threadIdx.x & 63;      // wave spans the full 256-col row
    const int ty   = threadIdx.x >> 6;      // 0..7, wave-uniform
    const int c0   = lane << 2;

    const int rt    = blockIdx.x & 7;
    const int plane = blockIdx.x >> 3;      // b*64 + c
    const int row0  = rt * TH;
    const int i0    = ty << 2;              // this thread's 4 output rows

    const float* xp = x + (size_t)plane * (size_t)(W * H);
    const int b = plane >> 6, cch = plane & 63;
    float* outx = out + ((size_t)(b * 128 + cch)) * (size_t)(W * H);
    float* outr = outx + (size_t)64 * (W * H);

    // ---- Phase 1a: load burst (4 own rows + optional 1 halo row) ----
    const float* rp = xp + (row0 + i0) * W + c0;    // own rows always in-plane
    float4 v0 = *(const float4*)(rp);
    float4 v1 = *(const float4*)(rp + W);
    float4 v2 = *(const float4*)(rp + 2 * W);
    float4 v3 = *(const float4*)(rp + 3 * W);

    // halo rows: ty 0..2 -> lr=ty (rows row0-3+ty); ty 5..7 -> lr=30+ty (rows row0+27+ty)
    float4 hv = make_float4(0.f, 0.f, 0.f, 0.f);
    const int hlr  = (ty <= 2) ? ty : (ty >= 5 ? 30 + ty : -1);
    const int hrow = row0 - 3 + hlr;
    if (hlr >= 0 && (unsigned)hrow < (unsigned)H)
        hv = *(const float4*)(xp + hrow * W + c0);

    // ---- Phase 1b: d = 0.5*exp(x^2-x), horizontal 7-sum via shuffles, LDS store ----
    auto stage = [&](float4 v, int lr) {    // wave-uniform call sites only
        float4 d;
        d.x = 0.5f * __expf(__fmaf_rn(v.x, v.x, -v.x));
        d.y = 0.5f * __expf(__fmaf_rn(v.y, v.y, -v.y));
        d.z = 0.5f * __expf(__fmaf_rn(v.z, v.z, -v.z));
        d.w = 0.5f * __expf(__fmaf_rn(v.w, v.w, -v.w));
        float dmy = __shfl_up(d.y, 1);
        float dmz = __shfl_up(d.z, 1);
        float dmw = __shfl_up(d.w, 1);
        float dpx = __shfl_down(d.x, 1);
        float dpy = __shfl_down(d.y, 1);
        float dpz = __shfl_down(d.z, 1);
        if (lane == 0)  { dmy = 0.f; dmz = 0.f; dmw = 0.f; }
        if (lane == 63) { dpx = 0.f; dpy = 0.f; dpz = 0.f; }
        const float s = (d.x + d.y) + (d.z + d.w);
        float4 h;
        h.x = ((dmy + dmz) + dmw) + s;
        h.y = (dmz + dmw) + (s + dpx);
        h.z = dmw + (s + (dpx + dpy));
        h.w = s + ((dpx + dpy) + dpz);
        *(float4*)&hs[lr][c0] = h;
    };

    stage(v0, i0 + 3);
    stage(v1, i0 + 4);
    stage(v2, i0 + 5);
    stage(v3, i0 + 6);
    if (hlr >= 0) stage(hv, hlr);           // zeros if OOB row

    // concat first half: copy of x, straight from registers (nt: nothing re-reads it)
    nt_store(outx + (size_t)(row0 + i0 + 0) * W + c0, v0);
    nt_store(outx + (size_t)(row0 + i0 + 1) * W + c0, v1);
    nt_store(outx + (size_t)(row0 + i0 + 2) * W + c0, v2);
    nt_store(outx + (size_t)(row0 + i0 + 3) * W + c0, v3);

    __syncthreads();

    // ---- Phase 2: sliding 7-row vertical window over hsums ----
    float4 rch;
    rch.x = __builtin_amdgcn_rcpf((float)(min(c0 + 3, W - 1) - max(c0 - 3, 0) + 1));
    rch.y = __builtin_amdgcn_rcpf((float)(min(c0 + 4, W - 1) - max(c0 - 2, 0) + 1));
    rch.z = __builtin_amdgcn_rcpf((float)(min(c0 + 5, W - 1) - max(c0 - 1, 0) + 1));
    rch.w = __builtin_amdgcn_rcpf((float)(min(c0 + 6, W - 1) - max(c0 + 0, 0) + 1));

    #define LDH(k) (*(const float4*)&hs[i0 + (k)][c0])

    float4 b0 = LDH(0), b1 = LDH(1), b2 = LDH(2);
    float4 t3 = LDH(3), t4 = LDH(4), t5 = LDH(5), t6 = LDH(6);
    float4 vs;
    vs.x = ((b0.x + b1.x) + (b2.x + t3.x)) + ((t4.x + t5.x) + t6.x);
    vs.y = ((b0.y + b1.y) + (b2.y + t3.y)) + ((t4.y + t5.y) + t6.y);
    vs.z = ((b0.z + b1.z) + (b2.z + t3.z)) + ((t4.z + t5.z) + t6.z);
    vs.w = ((b0.w + b1.w) + (b2.w + t3.w)) + ((t4.w + t5.w) + t6.w);

    auto emit = [&](int j, const float4& s) {
        const int row = row0 + i0 + j;
        const float rcv = __builtin_amdgcn_rcpf(
            (float)(min(row + 3, H - 1) - max(row - 3, 0) + 1));
        float4 xv = *(const float4*)(xp + row * W + c0);   // L1/L2-hot reload
        float4 r;
        r.x = s.x * (rch.x * rcv) * __expf(xv.x);
        r.y = s.y * (rch.y * rcv) * __expf(xv.y);
        r.z = s.z * (rch.z * rcv) * __expf(xv.z);
        r.w = s.w * (rch.w * rcv) * __expf(xv.w);
        nt_store(outr + (size_t)row * W + c0, r);
    };

    emit(0, vs);
    float4 tn = LDH(7);
    vs.x = (vs.x - b0.x) + tn.x;
    vs.y = (vs.y - b0.y) + tn.y;
    vs.z = (vs.z - b0.z) + tn.z;
    vs.w = (vs.w - b0.w) + tn.w;
    emit(1, vs);
    tn = LDH(8);
    vs.x = (vs.x - b1.x) + tn.x;
    vs.y = (vs.y - b1.y) + tn.y;
    vs.z = (vs.z - b1.z) + tn.z;
    vs.w = (vs.w - b1.w) + tn.w;
    emit(2, vs);
    tn = LDH(9);
    vs.x = (vs.x - b2.x) + tn.x;
    vs.y = (vs.y - b2.y) + tn.y;
    vs.z = (vs.z - b2.z) + tn.z;
    vs.w = (vs.w - b2.w) + tn.w;
    emit(3, vs);

    #undef LDH
}

extern "C" void kernel_launch(void* const* d_in, const int* in_sizes, int n_in,
                              void* d_out, int out_size, void* d_ws, size_t ws_size,
                              hipStream_t stream) {
    const float* x = (const float*)d_in[0];
    float* out = (float*)d_out;
    int n = in_sizes[0];
    int planes = n / (W * H);               // 512
    int grid = planes * (H / TH);           // 4096
    rg_kernel<<<dim3(grid), dim3(512), 0, stream>>>(x, out);
}

// Round 7
// 66.546 us; speedup vs baseline: 1.4067x; 1.0826x over previous
//
#include <hip/hip_runtime.h>

#define W   256
#define H   256
#define TH  32                  // output rows per block
#define NR  38                  // staged hsum rows (32 + 2*3 halo)

typedef float f4 __attribute__((ext_vector_type(4)));   // clang vector: ok for nontemporal builtins

__device__ __forceinline__ void nt_store(float* p, float4 v) {
    f4 t; t.x = v.x; t.y = v.y; t.z = v.z; t.w = v.w;
    __builtin_nontemporal_store(t, (f4*)p);
}

__global__ __launch_bounds__(512, 8)
void rg_kernel(const float* __restrict__ x, float* __restrict__ out) {
    __shared__ float hs[NR][W];             // horizontal 7-sums, 38 KB

    const int lane = threadIdx.x & 63;      // wave spans the full 256-col row
    const int ty   = threadIdx.x >> 6;      // 0..7, wave-uniform
    const int c0   = lane << 2;

    // XCD-aware swizzle: all 8 row-tiles of a plane -> same (idx mod 8) -> same XCD,
    // and within a 64-index window -> temporally co-resident, halo rows L2-hit.
    const int pg    = blockIdx.x & 7;       // plane-in-group
    const int rt    = (blockIdx.x >> 3) & 7;// row tile within plane
    const int plane = ((blockIdx.x >> 6) << 3) + pg;    // b*64 + c
    const int row0  = rt * TH;
    const int i0    = ty << 2;              // this thread's 4 output rows

    const float* xp = x + (size_t)plane * (size_t)(W * H);
    const int b = plane >> 6, cch = plane & 63;
    float* outx = out + ((size_t)(b * 128 + cch)) * (size_t)(W * H);
    float* outr = outx + (size_t)64 * (W * H);

    // ---- Phase 1a: load burst (4 own rows + optional 1 halo row) ----
    const float* rp = xp + (row0 + i0) * W + c0;    // own rows always in-plane
    float4 v0 = *(const float4*)(rp);
    float4 v1 = *(const float4*)(rp + W);
    float4 v2 = *(const float4*)(rp + 2 * W);
    float4 v3 = *(const float4*)(rp + 3 * W);

    // halo rows: ty 0..2 -> lr=ty (rows row0-3+ty); ty 5..7 -> lr=30+ty (rows row0+27+ty)
    float4 hv = make_float4(0.f, 0.f, 0.f, 0.f);
    const int hlr  = (ty <= 2) ? ty : (ty >= 5 ? 30 + ty : -1);
    const int hrow = row0 - 3 + hlr;
    if (hlr >= 0 && (unsigned)hrow < (unsigned)H)
        hv = *(const float4*)(xp + hrow * W + c0);

    // ---- Phase 1b: d = 0.5*exp(x^2-x), horizontal 7-sum via shuffles, LDS store ----
    auto stage = [&](float4 v, int lr) {    // wave-uniform call sites only
        float4 d;
        d.x = 0.5f * __expf(__fmaf_rn(v.x, v.x, -v.x));
        d.y = 0.5f * __expf(__fmaf_rn(v.y, v.y, -v.y));
        d.z = 0.5f * __expf(__fmaf_rn(v.z, v.z, -v.z));
        d.w = 0.5f * __expf(__fmaf_rn(v.w, v.w, -v.w));
        float dmy = __shfl_up(d.y, 1);
        float dmz = __shfl_up(d.z, 1);
        float dmw = __shfl_up(d.w, 1);
        float dpx = __shfl_down(d.x, 1);
        float dpy = __shfl_down(d.y, 1);
        float dpz = __shfl_down(d.z, 1);
        if (lane == 0)  { dmy = 0.f; dmz = 0.f; dmw = 0.f; }
        if (lane == 63) { dpx = 0.f; dpy = 0.f; dpz = 0.f; }
        const float s = (d.x + d.y) + (d.z + d.w);
        float4 h;
        h.x = ((dmy + dmz) + dmw) + s;
        h.y = (dmz + dmw) + (s + dpx);
        h.z = dmw + (s + (dpx + dpy));
        h.w = s + ((dpx + dpy) + dpz);
        *(float4*)&hs[lr][c0] = h;
    };

    stage(v0, i0 + 3);
    stage(v1, i0 + 4);
    stage(v2, i0 + 5);
    stage(v3, i0 + 6);
    if (hlr >= 0) stage(hv, hlr);           // zeros if OOB row

    // concat first half: copy of x, straight from registers (nt: nothing re-reads it)
    nt_store(outx + (size_t)(row0 + i0 + 0) * W + c0, v0);
    nt_store(outx + (size_t)(row0 + i0 + 1) * W + c0, v1);
    nt_store(outx + (size_t)(row0 + i0 + 2) * W + c0, v2);
    nt_store(outx + (size_t)(row0 + i0 + 3) * W + c0, v3);

    __syncthreads();

    // ---- Phase 2: sliding 7-row vertical window over hsums ----
    float4 rch;
    rch.x = __builtin_amdgcn_rcpf((float)(min(c0 + 3, W - 1) - max(c0 - 3, 0) + 1));
    rch.y = __builtin_amdgcn_rcpf((float)(min(c0 + 4, W - 1) - max(c0 - 2, 0) + 1));
    rch.z = __builtin_amdgcn_rcpf((float)(min(c0 + 5, W - 1) - max(c0 - 1, 0) + 1));
    rch.w = __builtin_amdgcn_rcpf((float)(min(c0 + 6, W - 1) - max(c0 + 0, 0) + 1));

    #define LDH(k) (*(const float4*)&hs[i0 + (k)][c0])

    float4 b0 = LDH(0), b1 = LDH(1), b2 = LDH(2);
    float4 t3 = LDH(3), t4 = LDH(4), t5 = LDH(5), t6 = LDH(6);
    float4 vs;
    vs.x = ((b0.x + b1.x) + (b2.x + t3.x)) + ((t4.x + t5.x) + t6.x);
    vs.y = ((b0.y + b1.y) + (b2.y + t3.y)) + ((t4.y + t5.y) + t6.y);
    vs.z = ((b0.z + b1.z) + (b2.z + t3.z)) + ((t4.z + t5.z) + t6.z);
    vs.w = ((b0.w + b1.w) + (b2.w + t3.w)) + ((t4.w + t5.w) + t6.w);

    auto emit = [&](int j, const float4& s) {
        const int row = row0 + i0 + j;
        const float rcv = __builtin_amdgcn_rcpf(
            (float)(min(row + 3, H - 1) - max(row - 3, 0) + 1));
        float4 xv = *(const float4*)(xp + row * W + c0);   // L1/L2-hot reload
        float4 r;
        r.x = s.x * (rch.x * rcv) * __expf(xv.x);
        r.y = s.y * (rch.y * rcv) * __expf(xv.y);
        r.z = s.z * (rch.z * rcv) * __expf(xv.z);
        r.w = s.w * (rch.w * rcv) * __expf(xv.w);
        nt_store(outr + (size_t)row * W + c0, r);
    };

    emit(0, vs);
    float4 tn = LDH(7);
    vs.x = (vs.x - b0.x) + tn.x;
    vs.y = (vs.y - b0.y) + tn.y;
    vs.z = (vs.z - b0.z) + tn.z;
    vs.w = (vs.w - b0.w) + tn.w;
    emit(1, vs);
    tn = LDH(8);
    vs.x = (vs.x - b1.x) + tn.x;
    vs.y = (vs.y - b1.y) + tn.y;
    vs.z = (vs.z - b1.z) + tn.z;
    vs.w = (vs.w - b1.w) + tn.w;
    emit(2, vs);
    tn = LDH(9);
    vs.x = (vs.x - b2.x) + tn.x;
    vs.y = (vs.y - b2.y) + tn.y;
    vs.z = (vs.z - b2.z) + tn.z;
    vs.w = (vs.w - b2.w) + tn.w;
    emit(3, vs);

    #undef LDH
}

extern "C" void kernel_launch(void* const* d_in, const int* in_sizes, int n_in,
                              void* d_out, int out_size, void* d_ws, size_t ws_size,
                              hipStream_t stream) {
    const float* x = (const float*)d_in[0];
    float* out = (float*)d_out;
    int n = in_sizes[0];
    int planes = n / (W * H);               // 512
    int grid = planes * (H / TH);           // 4096
    rg_kernel<<<dim3(grid), dim3(512), 0, stream>>>(x, out);
}